// Round 16
// baseline (171.547 us; speedup 1.0000x reference)
//
#include <hip/hip_runtime.h>
#include <hip/hip_bf16.h>

// CrissCrossAttention: B=4, C=512, H=W=64. v10 = v9 + k_energy ky-batching + projv swizzle.
//   k_out (80us, LDS-throughput-bound): unchanged from v9.
//   k_energy v2: 4 ky per block (Q staged once, frags hoisted to regs; K dbuf vmcnt(2));
//                XCD swizzle co-locates the 32 w-blocks sharing each K panel.
//   k_projv: + XCD swizzle co-locating the 4 m0-blocks per n0 (xT L2 dedup).

typedef __bf16 bf16_t;
typedef __bf16 bf16x8 __attribute__((ext_vector_type(8)));
typedef __bf16 bf16x4 __attribute__((ext_vector_type(4)));
typedef float f32x4 __attribute__((ext_vector_type(4)));

#define HW_ 4096
#define CIN 512
#define CQ 64

__device__ __forceinline__ void gload16(const void* g, void* l) {
  __builtin_amdgcn_global_load_lds((const __attribute__((address_space(1))) void*)g,
                                   (__attribute__((address_space(3))) void*)l, 16, 0, 0);
}

// ---------------- weights pack ----------------
__global__ __launch_bounds__(256) void k_wcat(const float* __restrict__ wq,
                                              const float* __restrict__ wk,
                                              const float* __restrict__ wv,
                                              bf16_t* __restrict__ Wcat) {
  int idx = (blockIdx.x * 256 + threadIdx.x) * 4;
  int row = idx >> 9, c = idx & 511;
  const float* src;
  if (row < 64)       src = wq + row * 512 + c;
  else if (row < 128) src = wk + (row - 64) * 512 + c;
  else                src = wv + (row - 128) * 512 + c;
  float4 v = *(const float4*)src;
  bf16x4 o = { (bf16_t)v.x, (bf16_t)v.y, (bf16_t)v.z, (bf16_t)v.w };
  *(bf16x4*)&Wcat[idx] = o;
}

// ---------------- x transpose + bf16 ----------------
__global__ __launch_bounds__(256) void k_prep(const float* __restrict__ x, bf16_t* __restrict__ xT) {
  __shared__ float tile[64][65];
  const int b = blockIdx.z;
  const int p0 = blockIdx.x * 64, c0 = blockIdx.y * 64;
  const float* xb = x + (size_t)b * CIN * HW_;
  bf16_t* xTb = xT + (size_t)b * HW_ * CIN;
  const int tid = threadIdx.x;
  const int r = tid >> 4, q = tid & 15;
#pragma unroll
  for (int i = 0; i < 4; ++i) {
    int lr = r + 16 * i;
    float4 v = *(const float4*)&xb[(size_t)(c0 + lr) * HW_ + p0 + q * 4];
    tile[lr][q * 4 + 0] = v.x; tile[lr][q * 4 + 1] = v.y;
    tile[lr][q * 4 + 2] = v.z; tile[lr][q * 4 + 3] = v.w;
  }
  __syncthreads();
#pragma unroll
  for (int i = 0; i < 4; ++i) {
    int pr = r + 16 * i;
    bf16x4 o;
    o[0] = (bf16_t)tile[q * 4 + 0][pr];
    o[1] = (bf16_t)tile[q * 4 + 1][pr];
    o[2] = (bf16_t)tile[q * 4 + 2][pr];
    o[3] = (bf16_t)tile[q * 4 + 3][pr];
    *(bf16x4*)&xTb[(size_t)(p0 + pr) * CIN + c0 + q * 4] = o;
  }
}

// ---------------- q/k projection GEMM (Wcat rows 0..127) ----------------
__global__ __launch_bounds__(256) void k_projqk(const bf16_t* __restrict__ Wcat,
                                                const bf16_t* __restrict__ xT,
                                                const float* __restrict__ bq,
                                                const float* __restrict__ bk,
                                                bf16_t* __restrict__ qfT,
                                                bf16_t* __restrict__ kfT) {
  __shared__ bf16_t As[128][64];
  __shared__ bf16_t Bs[128][64];
  const int b = blockIdx.z;
  const int n0 = blockIdx.x * 128;
  const char* Wb = (const char*)Wcat;
  const char* Xb = (const char*)(xT + (size_t)b * HW_ * CIN);
  const int tid = threadIdx.x, wv_ = tid >> 6, lane = tid & 63;
  const int wm = wv_ >> 1, wn = wv_ & 1;
  const int g = lane >> 4, cc = lane & 15;
  f32x4 acc[4][4]{};
  for (int ks = 0; ks < 512; ks += 64) {
    if (ks) __syncthreads();
#pragma unroll
    for (int i = 0; i < 4; ++i) {
      int ch = wv_ * 4 + i;
      int rr = ch * 8 + (lane >> 3);
      int sl = (lane & 7) ^ (rr & 7);
      gload16(Wb + (size_t)rr * 1024 + ks * 2 + sl * 16, (char*)As + ch * 1024);
      gload16(Xb + (size_t)(n0 + rr) * 1024 + ks * 2 + sl * 16, (char*)Bs + ch * 1024);
    }
    __syncthreads();
#pragma unroll
    for (int k2 = 0; k2 < 2; ++k2) {
      bf16x8 a[4], bb[4];
#pragma unroll
      for (int f = 0; f < 4; ++f)
        a[f] = *(const bf16x8*)((char*)As + (wm * 64 + f * 16 + cc) * 128 + (((k2 * 4 + g) ^ (cc & 7)) * 16));
#pragma unroll
      for (int f = 0; f < 4; ++f)
        bb[f] = *(const bf16x8*)((char*)Bs + (wn * 64 + f * 16 + cc) * 128 + (((k2 * 4 + g) ^ (cc & 7)) * 16));
#pragma unroll
      for (int fm = 0; fm < 4; ++fm)
#pragma unroll
        for (int fn = 0; fn < 4; ++fn)
          acc[fm][fn] = __builtin_amdgcn_mfma_f32_16x16x32_bf16(a[fm], bb[fn], acc[fm][fn], 0, 0, 0);
    }
  }
  bf16_t* qb = qfT + (size_t)b * HW_ * CQ;
  bf16_t* kb = kfT + (size_t)b * HW_ * CQ;
#pragma unroll
  for (int fm = 0; fm < 4; ++fm) {
#pragma unroll
    for (int j = 0; j < 4; ++j) {
      int m = wm * 64 + fm * 16 + g * 4 + j;
      float bias = (m < 64) ? bq[m] : bk[m - 64];
#pragma unroll
      for (int fn = 0; fn < 4; ++fn) {
        int n = n0 + wn * 64 + fn * 16 + cc;
        float val = acc[fm][fn][j] + bias;
        if (m < 64) qb[(size_t)n * CQ + m] = (bf16_t)val;
        else        kb[(size_t)n * CQ + (m - 64)] = (bf16_t)val;
      }
    }
  }
}

// ---------------- V projection GEMM (Wcat rows 128..639, permuted pixels) ----------------
// XCD swizzle: each XCD gets 32 n0 x 2 m0 (B-tile L2 dedup: xT read 128->~64MB).
__global__ __launch_bounds__(256) void k_projv(const bf16_t* __restrict__ Wcat,
                                               const bf16_t* __restrict__ xT,
                                               const float* __restrict__ bv,
                                               bf16_t* __restrict__ Vp2) {
  __shared__ bf16_t As[128][64];
  __shared__ bf16_t Bs[128][64];
  const int lin = blockIdx.x + blockIdx.y * 32 + blockIdx.z * 128;
  const int orig = (lin & 7) * 64 + (lin >> 3);   // bijective: 512 = 8*64
  const int bx = orig & 31, by = (orig >> 5) & 3, b = orig >> 7;
  const int n0 = bx * 128, m0 = by * 128;
  const char* Wb = (const char*)Wcat;
  const char* Xb = (const char*)(xT + (size_t)b * HW_ * CIN);
  const int tid = threadIdx.x, wv_ = tid >> 6, lane = tid & 63;
  const int wm = wv_ >> 1, wn = wv_ & 1;
  const int g = lane >> 4, cc = lane & 15;
  f32x4 acc[4][4]{};
  for (int ks = 0; ks < 512; ks += 64) {
    if (ks) __syncthreads();
#pragma unroll
    for (int i = 0; i < 4; ++i) {
      int ch = wv_ * 4 + i;
      int rr = ch * 8 + (lane >> 3);
      int sl = (lane & 7) ^ (rr & 7);
      int pix = (rr & 63) * 64 + (bx * 2) + (rr >> 6);  // perm(n0+rr)
      gload16(Wb + (size_t)(128 + m0 + rr) * 1024 + ks * 2 + sl * 16, (char*)As + ch * 1024);
      gload16(Xb + (size_t)pix * 1024 + ks * 2 + sl * 16, (char*)Bs + ch * 1024);
    }
    __syncthreads();
#pragma unroll
    for (int k2 = 0; k2 < 2; ++k2) {
      bf16x8 a[4], bb[4];
#pragma unroll
      for (int f = 0; f < 4; ++f)
        a[f] = *(const bf16x8*)((char*)As + (wm * 64 + f * 16 + cc) * 128 + (((k2 * 4 + g) ^ (cc & 7)) * 16));
#pragma unroll
      for (int f = 0; f < 4; ++f)
        bb[f] = *(const bf16x8*)((char*)Bs + (wn * 64 + f * 16 + cc) * 128 + (((k2 * 4 + g) ^ (cc & 7)) * 16));
#pragma unroll
      for (int fm = 0; fm < 4; ++fm)
#pragma unroll
        for (int fn = 0; fn < 4; ++fn)
          acc[fm][fn] = __builtin_amdgcn_mfma_f32_16x16x32_bf16(a[fm], bb[fn], acc[fm][fn], 0, 0, 0);
    }
  }
  bf16_t* Vb = Vp2 + (size_t)b * CIN * HW_;
#pragma unroll
  for (int fm = 0; fm < 4; ++fm) {
#pragma unroll
    for (int j = 0; j < 4; ++j) {
      int m = m0 + wm * 64 + fm * 16 + g * 4 + j;
      float bias = bv[m];
#pragma unroll
      for (int fn = 0; fn < 4; ++fn) {
        int n = n0 + wn * 64 + fn * 16 + cc;
        Vb[(size_t)m * HW_ + n] = (bf16_t)(acc[fm][fn][j] + bias);
      }
    }
  }
}

// ---------------- energy v2 + softmax(v) -> Pt[b][w][k][v][h] ----------------
// Block: m-tile 128 pixels (2w x 64h), 4 ky per block. Q staged once (16KB),
// frags hoisted to regs; K dbuf 2x8KB, vmcnt(2). XCD swizzle: co-locate the
// 32 w-blocks sharing each K panel.
__global__ __launch_bounds__(256) void k_energy(const bf16_t* __restrict__ qfT,
                                                const bf16_t* __restrict__ kfT,
                                                bf16_t* __restrict__ Pt, int zbase) {
  __shared__ bf16_t Qs[8192];       // 16KB
  __shared__ bf16_t Ks[2][4096];    // 2x8KB
  const int lin = blockIdx.x + blockIdx.y * 32 + blockIdx.z * 512;
  const int total = 512 * gridDim.z, chunk = total >> 3;
  const int orig = (lin & 7) * chunk + (lin >> 3);  // bijective
  const int bx = orig & 31, by = (orig >> 5) & 15, bz = orig >> 9;
  const int b = zbase + bz;
  const int w0 = bx * 2, ky0 = by * 4;
  const char* qb = (const char*)(qfT + (size_t)b * HW_ * CQ);
  const char* kb = (const char*)(kfT + (size_t)b * HW_ * CQ);
  bf16_t* Ptb = Pt + (size_t)bz * 16777216;
  const int tid = threadIdx.x, wv_ = tid >> 6, lane = tid & 63;
  const int g = lane >> 4, cc = lane & 15;

  // stage Q (pixels h*64 + w0 + dw) and K(ky0)
#pragma unroll
  for (int i = 0; i < 4; ++i) {
    int ch = wv_ * 4 + i;
    int rr = ch * 8 + (lane >> 3);
    int sl = (lane & 7) ^ (rr & 7);
    int pix = (rr & 63) * 64 + w0 + (rr >> 6);
    gload16(qb + (size_t)pix * 128 + sl * 16, (char*)Qs + ch * 1024);
  }
#pragma unroll
  for (int i = 0; i < 2; ++i) {
    int ch = wv_ * 2 + i;
    int rr = ch * 8 + (lane >> 3);
    int sl = (lane & 7) ^ (rr & 7);
    gload16(kb + (size_t)(ky0 * 64 + rr) * 128 + sl * 16, (char*)Ks[0] + ch * 1024);
  }
  asm volatile("s_waitcnt vmcnt(0)" ::: "memory");
  __builtin_amdgcn_s_barrier();

  // hoist Q-frags (m-strip rows [wv_*32, wv_*32+32))
  bf16x8 qf[2][2];
#pragma unroll
  for (int fm = 0; fm < 2; ++fm)
#pragma unroll
    for (int k2 = 0; k2 < 2; ++k2)
      qf[fm][k2] = *(const bf16x8*)((char*)Qs + (wv_ * 32 + fm * 16 + cc) * 128 +
                                    (((k2 * 4 + g) ^ (cc & 7)) * 16));

  const int w = w0 + (wv_ >> 1);
  for (int kq = 0; kq < 4; ++kq) {
    const int cur = kq & 1;
    if (kq < 3) {
      const int nxt = cur ^ 1;
#pragma unroll
      for (int i = 0; i < 2; ++i) {
        int ch = wv_ * 2 + i;
        int rr = ch * 8 + (lane >> 3);
        int sl = (lane & 7) ^ (rr & 7);
        gload16(kb + (size_t)((ky0 + kq + 1) * 64 + rr) * 128 + sl * 16, (char*)Ks[nxt] + ch * 1024);
      }
      asm volatile("s_waitcnt vmcnt(2)" ::: "memory");
    } else {
      asm volatile("s_waitcnt vmcnt(0)" ::: "memory");
    }
    __builtin_amdgcn_s_barrier();   // K(kq) ready

    f32x4 acc[2][4]{};
#pragma unroll
    for (int k2 = 0; k2 < 2; ++k2) {
      bf16x8 kf[4];
#pragma unroll
      for (int f = 0; f < 4; ++f)
        kf[f] = *(const bf16x8*)((char*)Ks[cur] + (f * 16 + cc) * 128 + (((k2 * 4 + g) ^ (cc & 7)) * 16));
#pragma unroll
      for (int fm = 0; fm < 2; ++fm)
#pragma unroll
        for (int fn = 0; fn < 4; ++fn)
          acc[fm][fn] = __builtin_amdgcn_mfma_f32_16x16x32_bf16(qf[fm][k2], kf[fn], acc[fm][fn], 0, 0, 0);
    }
#pragma unroll
    for (int fm = 0; fm < 2; ++fm) {
      float e[4][4], invj[4];
#pragma unroll
      for (int j = 0; j < 4; ++j) {
        float mx = fmaxf(fmaxf(acc[fm][0][j], acc[fm][1][j]), fmaxf(acc[fm][2][j], acc[fm][3][j]));
#pragma unroll
        for (int d = 1; d < 16; d <<= 1) mx = fmaxf(mx, __shfl_xor(mx, d, 64));
        float s = 0.f;
#pragma unroll
        for (int fn = 0; fn < 4; ++fn) { e[fn][j] = __expf(acc[fm][fn][j] - mx); s += e[fn][j]; }
#pragma unroll
        for (int d = 1; d < 16; d <<= 1) s += __shfl_xor(s, d, 64);
        invj[j] = __builtin_amdgcn_rcpf(s);
      }
      int h0 = (wv_ & 1) * 32 + fm * 16 + g * 4;
#pragma unroll
      for (int fn = 0; fn < 4; ++fn) {
        int v = fn * 16 + cc;
        bf16x4 pk = { (bf16_t)(e[fn][0] * invj[0]), (bf16_t)(e[fn][1] * invj[1]),
                      (bf16_t)(e[fn][2] * invj[2]), (bf16_t)(e[fn][3] * invj[3]) };
        *(bf16x4*)&Ptb[(((size_t)w * 64 + (ky0 + kq)) * 64 + v) * 64 + h0] = pk;
      }
    }
    asm volatile("s_waitcnt lgkmcnt(0)" ::: "memory");
    __builtin_amdgcn_s_barrier();   // K(kq) reads done before buffer reuse
  }
}

// ---------------- out GEMM v9 + epilogue (unchanged) ----------------
__global__ __launch_bounds__(512) void k_out(const bf16_t* __restrict__ Vp2,
                                             const bf16_t* __restrict__ Pt,
                                             const float* __restrict__ x,
                                             const float* __restrict__ gamma,
                                             float* __restrict__ outp, int zbase) {
  __shared__ char Ls[98304];
  const int lin = blockIdx.x + (blockIdx.y << 1) + (blockIdx.z << 6);
  const int nwg8 = (gridDim.z == 4) ? 32 : 8;
  const int rsw = (lin & 7) * nwg8 + (lin >> 3);
  const int c0 = (rsw & 1) * 256;
  const int w0 = ((rsw >> 1) & 31) * 2;
  const int bz = (gridDim.z == 4) ? (rsw >> 6) : 0;
  const int b = zbase + bz;
  const char* Vb = (const char*)(Vp2 + (size_t)b * CIN * HW_);
  const char* Pb = (const char*)(Pt + (size_t)bz * 16777216);
  const int tid = threadIdx.x, wv_ = tid >> 6, lane = tid & 63;
  const int wm = wv_ >> 1, wn = wv_ & 1;
  const int g = lane >> 4, cc = lane & 15;

  const char* aSb[4]; const char* bSb[2];
#pragma unroll
  for (int r = 0; r < 4; ++r) {
    int L = (r * 8 + wv_) * 64 + lane;
    int arow = L >> 3, asl = (L & 7) ^ (arow & 7);
    aSb[r] = Vb + (size_t)(c0 + arow) * 8192 + asl * 16;
  }
#pragma unroll
  for (int r = 0; r < 2; ++r) {
    int L = (r * 8 + wv_) * 64 + lane;
    int ws = L >> 9, e = L & 511, v = e >> 3, bsl = (e & 7) ^ (v & 7);
    bSb[r] = Pb + (size_t)(w0 + ws) * 524288 + v * 128 + bsl * 16;
  }
  int aoff[2][4], boff[2][4];
#pragma unroll
  for (int k2 = 0; k2 < 2; ++k2) {
#pragma unroll
    for (int fm = 0; fm < 4; ++fm)
      aoff[k2][fm] = (wm * 64 + fm * 16 + cc) * 128 + (((k2 * 4 + g) ^ (cc & 7)) * 16);
#pragma unroll
    for (int fn = 0; fn < 4; ++fn)
      boff[k2][fn] = 65536 + wn * 8192 + (fn * 16 + cc) * 128 + (((k2 * 4 + g) ^ (cc & 7)) * 16);
  }

  f32x4 acc[4][4]{};
#pragma unroll
  for (int r = 0; r < 4; ++r) gload16(aSb[r], Ls + (r * 8 + wv_) * 1024);
#pragma unroll
  for (int r = 0; r < 2; ++r) gload16(bSb[r], Ls + 65536 + (r * 8 + wv_) * 1024);

  for (int s = 0; s < 64; ++s) {
    const int cur = s & 1;
    if (s < 63) {
      const int nxt = cur ^ 1;
#pragma unroll
      for (int r = 0; r < 4; ++r)
        gload16(aSb[r] + (size_t)(s + 1) * 128, Ls + nxt * 32768 + (r * 8 + wv_) * 1024);
#pragma unroll
      for (int r = 0; r < 2; ++r)
        gload16(bSb[r] + (size_t)(s + 1) * 8192, Ls + 65536 + nxt * 16384 + (r * 8 + wv_) * 1024);
      asm volatile("s_waitcnt vmcnt(6)" ::: "memory");
    } else {
      asm volatile("s_waitcnt vmcnt(0)" ::: "memory");
    }
    __builtin_amdgcn_s_barrier();
#pragma unroll
    for (int k2 = 0; k2 < 2; ++k2) {
      bf16x8 a[4], bb[4];
#pragma unroll
      for (int fm = 0; fm < 4; ++fm) a[fm] = *(const bf16x8*)(Ls + cur * 32768 + aoff[k2][fm]);
#pragma unroll
      for (int fn = 0; fn < 4; ++fn) bb[fn] = *(const bf16x8*)(Ls + cur * 16384 + boff[k2][fn]);
#pragma unroll
      for (int fm = 0; fm < 4; ++fm)
#pragma unroll
        for (int fn = 0; fn < 4; ++fn)
          acc[fm][fn] = __builtin_amdgcn_mfma_f32_16x16x32_bf16(a[fm], bb[fn], acc[fm][fn], 0, 0, 0);
    }
    asm volatile("s_waitcnt lgkmcnt(0)" ::: "memory");
    __builtin_amdgcn_s_barrier();
  }
  const float gmm = gamma[0];
  const float* xb = x + (size_t)b * CIN * HW_;
  float* ob = outp + (size_t)b * CIN * HW_;
  const int w = w0 + wn;
#pragma unroll
  for (int fm = 0; fm < 4; ++fm) {
#pragma unroll
    for (int jj = 0; jj < 4; ++jj) {
      int c = c0 + wm * 64 + fm * 16 + g * 4 + jj;
#pragma unroll
      for (int fn = 0; fn < 4; ++fn) {
        int n = w * 64 + fn * 16 + cc;
        size_t idx = (size_t)c * HW_ + n;
        ob[idx] = gmm * acc[fm][fn][jj] + xb[idx];
      }
    }
  }
}

extern "C" void kernel_launch(void* const* d_in, const int* in_sizes, int n_in,
                              void* d_out, int out_size, void* d_ws, size_t ws_size,
                              hipStream_t stream) {
  const float* x  = (const float*)d_in[0];
  const float* wq = (const float*)d_in[1];
  const float* bq = (const float*)d_in[2];
  const float* wk = (const float*)d_in[3];
  const float* bk = (const float*)d_in[4];
  const float* wv = (const float*)d_in[5];
  const float* bv = (const float*)d_in[6];
  const float* gamma = (const float*)d_in[7];
  float* outp = (float*)d_out;
  char* ws = (char*)d_ws;
  size_t off = 0;
  bf16_t* xT   = (bf16_t*)(ws + off); off += (size_t)4 * HW_ * CIN * 2;   // 16 MB
  bf16_t* Wcat = (bf16_t*)(ws + off); off += (size_t)640 * CIN * 2;       // 640 KB
  bf16_t* qfT  = (bf16_t*)(ws + off); off += (size_t)4 * HW_ * CQ * 2;    // 2 MB
  bf16_t* kfT  = (bf16_t*)(ws + off); off += (size_t)4 * HW_ * CQ * 2;    // 2 MB
  bf16_t* Vp2  = (bf16_t*)(ws + off); off += (size_t)4 * CIN * HW_ * 2;   // 16 MB
  bf16_t* Pt   = (bf16_t*)(ws + off);
  const size_t pbytes = (size_t)HW_ * HW_ * 2;                            // 32 MB / batch
  const bool full = (ws_size >= off + 4 * pbytes);

  k_wcat<<<dim3(320), dim3(256), 0, stream>>>(wq, wk, wv, Wcat);
  k_prep<<<dim3(64, 8, 4), dim3(256), 0, stream>>>(x, xT);
  k_projqk<<<dim3(32, 1, 4), dim3(256), 0, stream>>>(Wcat, xT, bq, bk, qfT, kfT);
  k_projv<<<dim3(32, 4, 4), dim3(256), 0, stream>>>(Wcat, xT, bv, Vp2);
  if (full) {
    k_energy<<<dim3(32, 16, 4), dim3(256), 0, stream>>>(qfT, kfT, Pt, 0);
    k_out<<<dim3(2, 32, 4), dim3(512), 0, stream>>>(Vp2, Pt, x, gamma, outp, 0);
  } else {
    for (int b = 0; b < 4; ++b) {
      k_energy<<<dim3(32, 16, 1), dim3(256), 0, stream>>>(qfT, kfT, Pt, b);
      k_out<<<dim3(2, 32, 1), dim3(512), 0, stream>>>(Vp2, Pt, x, gamma, outp, b);
    }
  }
}

// Round 17
// 170.660 us; speedup vs baseline: 1.0052x; 1.0052x over previous
//
#include <hip/hip_runtime.h>
#include <hip/hip_bf16.h>

// CrissCrossAttention: B=4, C=512, H=W=64. v11 = v10 + k_out triple-buffer/1-barrier.
//   k_out: 256c x (2w x 64v), 8 waves; LDS 144KB = 3 x (A 32KB | B 16KB);
//          1 barrier/step (WAR hazard at distance 3 covered by barrier(s-1..s)),
//          vmcnt(6) counted, loop unrolled x3 for literal buffer indices.
//   Everything else unchanged from v10 (validated, absmax 0.031).

typedef __bf16 bf16_t;
typedef __bf16 bf16x8 __attribute__((ext_vector_type(8)));
typedef __bf16 bf16x4 __attribute__((ext_vector_type(4)));
typedef float f32x4 __attribute__((ext_vector_type(4)));

#define HW_ 4096
#define CIN 512
#define CQ 64

__device__ __forceinline__ void gload16(const void* g, void* l) {
  __builtin_amdgcn_global_load_lds((const __attribute__((address_space(1))) void*)g,
                                   (__attribute__((address_space(3))) void*)l, 16, 0, 0);
}

// ---------------- weights pack ----------------
__global__ __launch_bounds__(256) void k_wcat(const float* __restrict__ wq,
                                              const float* __restrict__ wk,
                                              const float* __restrict__ wv,
                                              bf16_t* __restrict__ Wcat) {
  int idx = (blockIdx.x * 256 + threadIdx.x) * 4;
  int row = idx >> 9, c = idx & 511;
  const float* src;
  if (row < 64)       src = wq + row * 512 + c;
  else if (row < 128) src = wk + (row - 64) * 512 + c;
  else                src = wv + (row - 128) * 512 + c;
  float4 v = *(const float4*)src;
  bf16x4 o = { (bf16_t)v.x, (bf16_t)v.y, (bf16_t)v.z, (bf16_t)v.w };
  *(bf16x4*)&Wcat[idx] = o;
}

// ---------------- x transpose + bf16 ----------------
__global__ __launch_bounds__(256) void k_prep(const float* __restrict__ x, bf16_t* __restrict__ xT) {
  __shared__ float tile[64][65];
  const int b = blockIdx.z;
  const int p0 = blockIdx.x * 64, c0 = blockIdx.y * 64;
  const float* xb = x + (size_t)b * CIN * HW_;
  bf16_t* xTb = xT + (size_t)b * HW_ * CIN;
  const int tid = threadIdx.x;
  const int r = tid >> 4, q = tid & 15;
#pragma unroll
  for (int i = 0; i < 4; ++i) {
    int lr = r + 16 * i;
    float4 v = *(const float4*)&xb[(size_t)(c0 + lr) * HW_ + p0 + q * 4];
    tile[lr][q * 4 + 0] = v.x; tile[lr][q * 4 + 1] = v.y;
    tile[lr][q * 4 + 2] = v.z; tile[lr][q * 4 + 3] = v.w;
  }
  __syncthreads();
#pragma unroll
  for (int i = 0; i < 4; ++i) {
    int pr = r + 16 * i;
    bf16x4 o;
    o[0] = (bf16_t)tile[q * 4 + 0][pr];
    o[1] = (bf16_t)tile[q * 4 + 1][pr];
    o[2] = (bf16_t)tile[q * 4 + 2][pr];
    o[3] = (bf16_t)tile[q * 4 + 3][pr];
    *(bf16x4*)&xTb[(size_t)(p0 + pr) * CIN + c0 + q * 4] = o;
  }
}

// ---------------- q/k projection GEMM (Wcat rows 0..127) ----------------
__global__ __launch_bounds__(256) void k_projqk(const bf16_t* __restrict__ Wcat,
                                                const bf16_t* __restrict__ xT,
                                                const float* __restrict__ bq,
                                                const float* __restrict__ bk,
                                                bf16_t* __restrict__ qfT,
                                                bf16_t* __restrict__ kfT) {
  __shared__ bf16_t As[128][64];
  __shared__ bf16_t Bs[128][64];
  const int b = blockIdx.z;
  const int n0 = blockIdx.x * 128;
  const char* Wb = (const char*)Wcat;
  const char* Xb = (const char*)(xT + (size_t)b * HW_ * CIN);
  const int tid = threadIdx.x, wv_ = tid >> 6, lane = tid & 63;
  const int wm = wv_ >> 1, wn = wv_ & 1;
  const int g = lane >> 4, cc = lane & 15;
  f32x4 acc[4][4]{};
  for (int ks = 0; ks < 512; ks += 64) {
    if (ks) __syncthreads();
#pragma unroll
    for (int i = 0; i < 4; ++i) {
      int ch = wv_ * 4 + i;
      int rr = ch * 8 + (lane >> 3);
      int sl = (lane & 7) ^ (rr & 7);
      gload16(Wb + (size_t)rr * 1024 + ks * 2 + sl * 16, (char*)As + ch * 1024);
      gload16(Xb + (size_t)(n0 + rr) * 1024 + ks * 2 + sl * 16, (char*)Bs + ch * 1024);
    }
    __syncthreads();
#pragma unroll
    for (int k2 = 0; k2 < 2; ++k2) {
      bf16x8 a[4], bb[4];
#pragma unroll
      for (int f = 0; f < 4; ++f)
        a[f] = *(const bf16x8*)((char*)As + (wm * 64 + f * 16 + cc) * 128 + (((k2 * 4 + g) ^ (cc & 7)) * 16));
#pragma unroll
      for (int f = 0; f < 4; ++f)
        bb[f] = *(const bf16x8*)((char*)Bs + (wn * 64 + f * 16 + cc) * 128 + (((k2 * 4 + g) ^ (cc & 7)) * 16));
#pragma unroll
      for (int fm = 0; fm < 4; ++fm)
#pragma unroll
        for (int fn = 0; fn < 4; ++fn)
          acc[fm][fn] = __builtin_amdgcn_mfma_f32_16x16x32_bf16(a[fm], bb[fn], acc[fm][fn], 0, 0, 0);
    }
  }
  bf16_t* qb = qfT + (size_t)b * HW_ * CQ;
  bf16_t* kb = kfT + (size_t)b * HW_ * CQ;
#pragma unroll
  for (int fm = 0; fm < 4; ++fm) {
#pragma unroll
    for (int j = 0; j < 4; ++j) {
      int m = wm * 64 + fm * 16 + g * 4 + j;
      float bias = (m < 64) ? bq[m] : bk[m - 64];
#pragma unroll
      for (int fn = 0; fn < 4; ++fn) {
        int n = n0 + wn * 64 + fn * 16 + cc;
        float val = acc[fm][fn][j] + bias;
        if (m < 64) qb[(size_t)n * CQ + m] = (bf16_t)val;
        else        kb[(size_t)n * CQ + (m - 64)] = (bf16_t)val;
      }
    }
  }
}

// ---------------- V projection GEMM (Wcat rows 128..639, permuted pixels) ----------------
__global__ __launch_bounds__(256) void k_projv(const bf16_t* __restrict__ Wcat,
                                               const bf16_t* __restrict__ xT,
                                               const float* __restrict__ bv,
                                               bf16_t* __restrict__ Vp2) {
  __shared__ bf16_t As[128][64];
  __shared__ bf16_t Bs[128][64];
  const int lin = blockIdx.x + blockIdx.y * 32 + blockIdx.z * 128;
  const int orig = (lin & 7) * 64 + (lin >> 3);   // bijective: 512 = 8*64
  const int bx = orig & 31, by = (orig >> 5) & 3, b = orig >> 7;
  const int n0 = bx * 128, m0 = by * 128;
  const char* Wb = (const char*)Wcat;
  const char* Xb = (const char*)(xT + (size_t)b * HW_ * CIN);
  const int tid = threadIdx.x, wv_ = tid >> 6, lane = tid & 63;
  const int wm = wv_ >> 1, wn = wv_ & 1;
  const int g = lane >> 4, cc = lane & 15;
  f32x4 acc[4][4]{};
  for (int ks = 0; ks < 512; ks += 64) {
    if (ks) __syncthreads();
#pragma unroll
    for (int i = 0; i < 4; ++i) {
      int ch = wv_ * 4 + i;
      int rr = ch * 8 + (lane >> 3);
      int sl = (lane & 7) ^ (rr & 7);
      int pix = (rr & 63) * 64 + (bx * 2) + (rr >> 6);  // perm(n0+rr)
      gload16(Wb + (size_t)(128 + m0 + rr) * 1024 + ks * 2 + sl * 16, (char*)As + ch * 1024);
      gload16(Xb + (size_t)pix * 1024 + ks * 2 + sl * 16, (char*)Bs + ch * 1024);
    }
    __syncthreads();
#pragma unroll
    for (int k2 = 0; k2 < 2; ++k2) {
      bf16x8 a[4], bb[4];
#pragma unroll
      for (int f = 0; f < 4; ++f)
        a[f] = *(const bf16x8*)((char*)As + (wm * 64 + f * 16 + cc) * 128 + (((k2 * 4 + g) ^ (cc & 7)) * 16));
#pragma unroll
      for (int f = 0; f < 4; ++f)
        bb[f] = *(const bf16x8*)((char*)Bs + (wn * 64 + f * 16 + cc) * 128 + (((k2 * 4 + g) ^ (cc & 7)) * 16));
#pragma unroll
      for (int fm = 0; fm < 4; ++fm)
#pragma unroll
        for (int fn = 0; fn < 4; ++fn)
          acc[fm][fn] = __builtin_amdgcn_mfma_f32_16x16x32_bf16(a[fm], bb[fn], acc[fm][fn], 0, 0, 0);
    }
  }
  bf16_t* Vb = Vp2 + (size_t)b * CIN * HW_;
#pragma unroll
  for (int fm = 0; fm < 4; ++fm) {
#pragma unroll
    for (int j = 0; j < 4; ++j) {
      int m = m0 + wm * 64 + fm * 16 + g * 4 + j;
      float bias = bv[m];
#pragma unroll
      for (int fn = 0; fn < 4; ++fn) {
        int n = n0 + wn * 64 + fn * 16 + cc;
        Vb[(size_t)m * HW_ + n] = (bf16_t)(acc[fm][fn][j] + bias);
      }
    }
  }
}

// ---------------- energy v2 + softmax(v) -> Pt[b][w][k][v][h] ----------------
__global__ __launch_bounds__(256) void k_energy(const bf16_t* __restrict__ qfT,
                                                const bf16_t* __restrict__ kfT,
                                                bf16_t* __restrict__ Pt, int zbase) {
  __shared__ bf16_t Qs[8192];       // 16KB
  __shared__ bf16_t Ks[2][4096];    // 2x8KB
  const int lin = blockIdx.x + blockIdx.y * 32 + blockIdx.z * 512;
  const int total = 512 * gridDim.z, chunk = total >> 3;
  const int orig = (lin & 7) * chunk + (lin >> 3);  // bijective
  const int bx = orig & 31, by = (orig >> 5) & 15, bz = orig >> 9;
  const int b = zbase + bz;
  const int w0 = bx * 2, ky0 = by * 4;
  const char* qb = (const char*)(qfT + (size_t)b * HW_ * CQ);
  const char* kb = (const char*)(kfT + (size_t)b * HW_ * CQ);
  bf16_t* Ptb = Pt + (size_t)bz * 16777216;
  const int tid = threadIdx.x, wv_ = tid >> 6, lane = tid & 63;
  const int g = lane >> 4, cc = lane & 15;

#pragma unroll
  for (int i = 0; i < 4; ++i) {
    int ch = wv_ * 4 + i;
    int rr = ch * 8 + (lane >> 3);
    int sl = (lane & 7) ^ (rr & 7);
    int pix = (rr & 63) * 64 + w0 + (rr >> 6);
    gload16(qb + (size_t)pix * 128 + sl * 16, (char*)Qs + ch * 1024);
  }
#pragma unroll
  for (int i = 0; i < 2; ++i) {
    int ch = wv_ * 2 + i;
    int rr = ch * 8 + (lane >> 3);
    int sl = (lane & 7) ^ (rr & 7);
    gload16(kb + (size_t)(ky0 * 64 + rr) * 128 + sl * 16, (char*)Ks[0] + ch * 1024);
  }
  asm volatile("s_waitcnt vmcnt(0)" ::: "memory");
  __builtin_amdgcn_s_barrier();

  bf16x8 qf[2][2];
#pragma unroll
  for (int fm = 0; fm < 2; ++fm)
#pragma unroll
    for (int k2 = 0; k2 < 2; ++k2)
      qf[fm][k2] = *(const bf16x8*)((char*)Qs + (wv_ * 32 + fm * 16 + cc) * 128 +
                                    (((k2 * 4 + g) ^ (cc & 7)) * 16));

  const int w = w0 + (wv_ >> 1);
  for (int kq = 0; kq < 4; ++kq) {
    const int cur = kq & 1;
    if (kq < 3) {
      const int nxt = cur ^ 1;
#pragma unroll
      for (int i = 0; i < 2; ++i) {
        int ch = wv_ * 2 + i;
        int rr = ch * 8 + (lane >> 3);
        int sl = (lane & 7) ^ (rr & 7);
        gload16(kb + (size_t)((ky0 + kq + 1) * 64 + rr) * 128 + sl * 16, (char*)Ks[nxt] + ch * 1024);
      }
      asm volatile("s_waitcnt vmcnt(2)" ::: "memory");
    } else {
      asm volatile("s_waitcnt vmcnt(0)" ::: "memory");
    }
    __builtin_amdgcn_s_barrier();

    f32x4 acc[2][4]{};
#pragma unroll
    for (int k2 = 0; k2 < 2; ++k2) {
      bf16x8 kf[4];
#pragma unroll
      for (int f = 0; f < 4; ++f)
        kf[f] = *(const bf16x8*)((char*)Ks[cur] + (f * 16 + cc) * 128 + (((k2 * 4 + g) ^ (cc & 7)) * 16));
#pragma unroll
      for (int fm = 0; fm < 2; ++fm)
#pragma unroll
        for (int fn = 0; fn < 4; ++fn)
          acc[fm][fn] = __builtin_amdgcn_mfma_f32_16x16x32_bf16(qf[fm][k2], kf[fn], acc[fm][fn], 0, 0, 0);
    }
#pragma unroll
    for (int fm = 0; fm < 2; ++fm) {
      float e[4][4], invj[4];
#pragma unroll
      for (int j = 0; j < 4; ++j) {
        float mx = fmaxf(fmaxf(acc[fm][0][j], acc[fm][1][j]), fmaxf(acc[fm][2][j], acc[fm][3][j]));
#pragma unroll
        for (int d = 1; d < 16; d <<= 1) mx = fmaxf(mx, __shfl_xor(mx, d, 64));
        float s = 0.f;
#pragma unroll
        for (int fn = 0; fn < 4; ++fn) { e[fn][j] = __expf(acc[fm][fn][j] - mx); s += e[fn][j]; }
#pragma unroll
        for (int d = 1; d < 16; d <<= 1) s += __shfl_xor(s, d, 64);
        invj[j] = __builtin_amdgcn_rcpf(s);
      }
      int h0 = (wv_ & 1) * 32 + fm * 16 + g * 4;
#pragma unroll
      for (int fn = 0; fn < 4; ++fn) {
        int v = fn * 16 + cc;
        bf16x4 pk = { (bf16_t)(e[fn][0] * invj[0]), (bf16_t)(e[fn][1] * invj[1]),
                      (bf16_t)(e[fn][2] * invj[2]), (bf16_t)(e[fn][3] * invj[3]) };
        *(bf16x4*)&Ptb[(((size_t)w * 64 + (ky0 + kq)) * 64 + v) * 64 + h0] = pk;
      }
    }
    asm volatile("s_waitcnt lgkmcnt(0)" ::: "memory");
    __builtin_amdgcn_s_barrier();
  }
}

// ---------------- out GEMM v11 + epilogue ----------------
// Block 256c x (2w x 64v), 8 waves. LDS 144KB = 3 buffers x (A 32KB | B 16KB).
// 1 barrier/step: WAR at buffer-distance 3 is covered by consecutive barriers
// (compute(s-2) ds_reads complete before its MFMAs, which precede barrier(s-1)).
#define KSTEP_S(s, cur, nxt) do {                                                            \
    _Pragma("unroll")                                                                        \
    for (int r = 0; r < 4; ++r)                                                              \
      gload16(aSb[r] + (size_t)((s) + 1) * 128, Ls + (nxt) * 49152 + (r * 8 + wv_) * 1024);  \
    _Pragma("unroll")                                                                        \
    for (int r = 0; r < 2; ++r)                                                              \
      gload16(bSb[r] + (size_t)((s) + 1) * 8192,                                             \
              Ls + (nxt) * 49152 + 32768 + (r * 8 + wv_) * 1024);                            \
    asm volatile("s_waitcnt vmcnt(6)" ::: "memory");                                         \
    __builtin_amdgcn_s_barrier();                                                            \
    COMPUTE(cur);                                                                            \
  } while (0)

#define COMPUTE(cur) do {                                                                    \
    const char* base_ = Ls + (cur) * 49152;                                                  \
    _Pragma("unroll")                                                                        \
    for (int k2 = 0; k2 < 2; ++k2) {                                                         \
      bf16x8 a[4], bb[4];                                                                    \
      _Pragma("unroll")                                                                      \
      for (int fm = 0; fm < 4; ++fm) a[fm] = *(const bf16x8*)(base_ + aoff[k2][fm]);         \
      _Pragma("unroll")                                                                      \
      for (int fn = 0; fn < 4; ++fn) bb[fn] = *(const bf16x8*)(base_ + boff[k2][fn]);        \
      _Pragma("unroll")                                                                      \
      for (int fm = 0; fm < 4; ++fm)                                                         \
        _Pragma("unroll")                                                                    \
        for (int fn = 0; fn < 4; ++fn)                                                       \
          acc[fm][fn] = __builtin_amdgcn_mfma_f32_16x16x32_bf16(a[fm], bb[fn], acc[fm][fn], 0, 0, 0); \
    }                                                                                        \
  } while (0)

__global__ __launch_bounds__(512) void k_out(const bf16_t* __restrict__ Vp2,
                                             const bf16_t* __restrict__ Pt,
                                             const float* __restrict__ x,
                                             const float* __restrict__ gamma,
                                             float* __restrict__ outp, int zbase) {
  __shared__ char Ls[147456];  // 3 x 48KB
  const int lin = blockIdx.x + (blockIdx.y << 1) + (blockIdx.z << 6);
  const int nwg8 = (gridDim.z == 4) ? 32 : 8;
  const int rsw = (lin & 7) * nwg8 + (lin >> 3);
  const int c0 = (rsw & 1) * 256;
  const int w0 = ((rsw >> 1) & 31) * 2;
  const int bz = (gridDim.z == 4) ? (rsw >> 6) : 0;
  const int b = zbase + bz;
  const char* Vb = (const char*)(Vp2 + (size_t)b * CIN * HW_);
  const char* Pb = (const char*)(Pt + (size_t)bz * 16777216);
  const int tid = threadIdx.x, wv_ = tid >> 6, lane = tid & 63;
  const int wm = wv_ >> 1, wn = wv_ & 1;
  const int g = lane >> 4, cc = lane & 15;

  const char* aSb[4]; const char* bSb[2];
#pragma unroll
  for (int r = 0; r < 4; ++r) {
    int L = (r * 8 + wv_) * 64 + lane;
    int arow = L >> 3, asl = (L & 7) ^ (arow & 7);
    aSb[r] = Vb + (size_t)(c0 + arow) * 8192 + asl * 16;
  }
#pragma unroll
  for (int r = 0; r < 2; ++r) {
    int L = (r * 8 + wv_) * 64 + lane;
    int ws = L >> 9, e = L & 511, v = e >> 3, bsl = (e & 7) ^ (v & 7);
    bSb[r] = Pb + (size_t)(w0 + ws) * 524288 + v * 128 + bsl * 16;
  }
  int aoff[2][4], boff[2][4];
#pragma unroll
  for (int k2 = 0; k2 < 2; ++k2) {
#pragma unroll
    for (int fm = 0; fm < 4; ++fm)
      aoff[k2][fm] = (wm * 64 + fm * 16 + cc) * 128 + (((k2 * 4 + g) ^ (cc & 7)) * 16);
#pragma unroll
    for (int fn = 0; fn < 4; ++fn)
      boff[k2][fn] = 32768 + wn * 8192 + (fn * 16 + cc) * 128 + (((k2 * 4 + g) ^ (cc & 7)) * 16);
  }

  f32x4 acc[4][4]{};
  // prologue: stage s=0 into buf0
#pragma unroll
  for (int r = 0; r < 4; ++r) gload16(aSb[r], Ls + (r * 8 + wv_) * 1024);
#pragma unroll
  for (int r = 0; r < 2; ++r) gload16(bSb[r], Ls + 32768 + (r * 8 + wv_) * 1024);

  int s = 0;
#pragma unroll 1
  for (int t = 0; t < 21; ++t) {    // s = 0..62, all stage s+1
    KSTEP_S(s, 0, 1);
    KSTEP_S(s + 1, 1, 2);
    KSTEP_S(s + 2, 2, 0);
    s += 3;
  }
  // s = 63 (63 % 3 == 0 -> buf0), no stage
  asm volatile("s_waitcnt vmcnt(0)" ::: "memory");
  __builtin_amdgcn_s_barrier();
  COMPUTE(0);

  const float gmm = gamma[0];
  const float* xb = x + (size_t)b * CIN * HW_;
  float* ob = outp + (size_t)b * CIN * HW_;
  const int w = w0 + wn;
#pragma unroll
  for (int fm = 0; fm < 4; ++fm) {
#pragma unroll
    for (int jj = 0; jj < 4; ++jj) {
      int c = c0 + wm * 64 + fm * 16 + g * 4 + jj;
#pragma unroll
      for (int fn = 0; fn < 4; ++fn) {
        int n = w * 64 + fn * 16 + cc;
        size_t idx = (size_t)c * HW_ + n;
        ob[idx] = gmm * acc[fm][fn][jj] + xb[idx];
      }
    }
  }
}

extern "C" void kernel_launch(void* const* d_in, const int* in_sizes, int n_in,
                              void* d_out, int out_size, void* d_ws, size_t ws_size,
                              hipStream_t stream) {
  const float* x  = (const float*)d_in[0];
  const float* wq = (const float*)d_in[1];
  const float* bq = (const float*)d_in[2];
  const float* wk = (const float*)d_in[3];
  const float* bk = (const float*)d_in[4];
  const float* wv = (const float*)d_in[5];
  const float* bv = (const float*)d_in[6];
  const float* gamma = (const float*)d_in[7];
  float* outp = (float*)d_out;
  char* ws = (char*)d_ws;
  size_t off = 0;
  bf16_t* xT   = (bf16_t*)(ws + off); off += (size_t)4 * HW_ * CIN * 2;   // 16 MB
  bf16_t* Wcat = (bf16_t*)(ws + off); off += (size_t)640 * CIN * 2;       // 640 KB
  bf16_t* qfT  = (bf16_t*)(ws + off); off += (size_t)4 * HW_ * CQ * 2;    // 2 MB
  bf16_t* kfT  = (bf16_t*)(ws + off); off += (size_t)4 * HW_ * CQ * 2;    // 2 MB
  bf16_t* Vp2  = (bf16_t*)(ws + off); off += (size_t)4 * CIN * HW_ * 2;   // 16 MB
  bf16_t* Pt   = (bf16_t*)(ws + off);
  const size_t pbytes = (size_t)HW_ * HW_ * 2;                            // 32 MB / batch
  const bool full = (ws_size >= off + 4 * pbytes);

  k_wcat<<<dim3(320), dim3(256), 0, stream>>>(wq, wk, wv, Wcat);
  k_prep<<<dim3(64, 8, 4), dim3(256), 0, stream>>>(x, xT);
  k_projqk<<<dim3(32, 1, 4), dim3(256), 0, stream>>>(Wcat, xT, bq, bk, qfT, kfT);
  k_projv<<<dim3(32, 4, 4), dim3(256), 0, stream>>>(Wcat, xT, bv, Vp2);
  if (full) {
    k_energy<<<dim3(32, 16, 4), dim3(256), 0, stream>>>(qfT, kfT, Pt, 0);
    k_out<<<dim3(2, 32, 4), dim3(512), 0, stream>>>(Vp2, Pt, x, gamma, outp, 0);
  } else {
    for (int b = 0; b < 4; ++b) {
      k_energy<<<dim3(32, 16, 1), dim3(256), 0, stream>>>(qfT, kfT, Pt, b);
      k_out<<<dim3(2, 32, 1), dim3(512), 0, stream>>>(Vp2, Pt, x, gamma, outp, b);
    }
  }
}

// Round 18
// 157.725 us; speedup vs baseline: 1.0876x; 1.0820x over previous
//
#include <hip/hip_runtime.h>
#include <hip/hip_bf16.h>

// CrissCrossAttention: B=4, C=512, H=W=64. v12 = v11 + merged projection kernel.
//   k_proj: ONE GEMM over Wcat rows 0..639, n-tiles = permuted pixels.
//           q/k stored PERMUTED: qfT2[w*64+h][m], kfT2[v*64+k][m] -> contiguous stores.
//           XCD swizzle cycles m-blocks fastest (B-panel read once per XCD).
//   k_energy: staging adapted (Q = 128 contiguous rows; K = stride-64 rows);
//             LDS contents identical to v10 -> fragments/softmax/P-write unchanged.
//   k_out: v11 triple-buffer 1-barrier (68.6us, validated).

typedef __bf16 bf16_t;
typedef __bf16 bf16x8 __attribute__((ext_vector_type(8)));
typedef __bf16 bf16x4 __attribute__((ext_vector_type(4)));
typedef float f32x4 __attribute__((ext_vector_type(4)));

#define HW_ 4096
#define CIN 512
#define CQ 64

__device__ __forceinline__ void gload16(const void* g, void* l) {
  __builtin_amdgcn_global_load_lds((const __attribute__((address_space(1))) void*)g,
                                   (__attribute__((address_space(3))) void*)l, 16, 0, 0);
}

// ---------------- weights pack ----------------
__global__ __launch_bounds__(256) void k_wcat(const float* __restrict__ wq,
                                              const float* __restrict__ wk,
                                              const float* __restrict__ wv,
                                              bf16_t* __restrict__ Wcat) {
  int idx = (blockIdx.x * 256 + threadIdx.x) * 4;
  int row = idx >> 9, c = idx & 511;
  const float* src;
  if (row < 64)       src = wq + row * 512 + c;
  else if (row < 128) src = wk + (row - 64) * 512 + c;
  else                src = wv + (row - 128) * 512 + c;
  float4 v = *(const float4*)src;
  bf16x4 o = { (bf16_t)v.x, (bf16_t)v.y, (bf16_t)v.z, (bf16_t)v.w };
  *(bf16x4*)&Wcat[idx] = o;
}

// ---------------- x transpose + bf16 ----------------
__global__ __launch_bounds__(256) void k_prep(const float* __restrict__ x, bf16_t* __restrict__ xT) {
  __shared__ float tile[64][65];
  const int b = blockIdx.z;
  const int p0 = blockIdx.x * 64, c0 = blockIdx.y * 64;
  const float* xb = x + (size_t)b * CIN * HW_;
  bf16_t* xTb = xT + (size_t)b * HW_ * CIN;
  const int tid = threadIdx.x;
  const int r = tid >> 4, q = tid & 15;
#pragma unroll
  for (int i = 0; i < 4; ++i) {
    int lr = r + 16 * i;
    float4 v = *(const float4*)&xb[(size_t)(c0 + lr) * HW_ + p0 + q * 4];
    tile[lr][q * 4 + 0] = v.x; tile[lr][q * 4 + 1] = v.y;
    tile[lr][q * 4 + 2] = v.z; tile[lr][q * 4 + 3] = v.w;
  }
  __syncthreads();
#pragma unroll
  for (int i = 0; i < 4; ++i) {
    int pr = r + 16 * i;
    bf16x4 o;
    o[0] = (bf16_t)tile[q * 4 + 0][pr];
    o[1] = (bf16_t)tile[q * 4 + 1][pr];
    o[2] = (bf16_t)tile[q * 4 + 2][pr];
    o[3] = (bf16_t)tile[q * 4 + 3][pr];
    *(bf16x4*)&xTb[(size_t)(p0 + pr) * CIN + c0 + q * 4] = o;
  }
}

// ---------------- merged projection GEMM (all 640 Wcat rows, permuted pixels) ----------------
// n-tile = permuted pixels p' in [n0, n0+128); pixel = perm(p') = (p'&63)*64 + (p'>>6).
// m-block by: rows [by*128, by*128+128). by==0 -> q/k (stored permuted-contiguous),
// by>=1 -> Vp2 rows m-128. XCD swizzle: by fastest -> B-panel read once per XCD.
__global__ __launch_bounds__(256) void k_proj(const bf16_t* __restrict__ Wcat,
                                              const bf16_t* __restrict__ xT,
                                              const float* __restrict__ bq,
                                              const float* __restrict__ bk,
                                              const float* __restrict__ bv,
                                              bf16_t* __restrict__ qfT2,
                                              bf16_t* __restrict__ kfT2,
                                              bf16_t* __restrict__ Vp2) {
  __shared__ bf16_t As[128][64];
  __shared__ bf16_t Bs[128][64];
  const int lin = blockIdx.x + blockIdx.y * 32 + blockIdx.z * 160;
  const int orig = (lin & 7) * 80 + (lin >> 3);   // bijective: 640 = 8*80
  const int by = orig % 5, bx = (orig / 5) & 31, b = orig / 160;
  const int n0 = bx * 128, m0 = by * 128;
  const char* Wb = (const char*)Wcat;
  const char* Xb = (const char*)(xT + (size_t)b * HW_ * CIN);
  const int tid = threadIdx.x, wv_ = tid >> 6, lane = tid & 63;
  const int wm = wv_ >> 1, wn = wv_ & 1;
  const int g = lane >> 4, cc = lane & 15;
  f32x4 acc[4][4]{};
  for (int ks = 0; ks < 512; ks += 64) {
    if (ks) __syncthreads();
#pragma unroll
    for (int i = 0; i < 4; ++i) {
      int ch = wv_ * 4 + i;
      int rr = ch * 8 + (lane >> 3);
      int sl = (lane & 7) ^ (rr & 7);
      int pix = (rr & 63) * 64 + (bx * 2) + (rr >> 6);  // perm(n0+rr)
      gload16(Wb + (size_t)(m0 + rr) * 1024 + ks * 2 + sl * 16, (char*)As + ch * 1024);
      gload16(Xb + (size_t)pix * 1024 + ks * 2 + sl * 16, (char*)Bs + ch * 1024);
    }
    __syncthreads();
#pragma unroll
    for (int k2 = 0; k2 < 2; ++k2) {
      bf16x8 a[4], bb[4];
#pragma unroll
      for (int f = 0; f < 4; ++f)
        a[f] = *(const bf16x8*)((char*)As + (wm * 64 + f * 16 + cc) * 128 + (((k2 * 4 + g) ^ (cc & 7)) * 16));
#pragma unroll
      for (int f = 0; f < 4; ++f)
        bb[f] = *(const bf16x8*)((char*)Bs + (wn * 64 + f * 16 + cc) * 128 + (((k2 * 4 + g) ^ (cc & 7)) * 16));
#pragma unroll
      for (int fm = 0; fm < 4; ++fm)
#pragma unroll
        for (int fn = 0; fn < 4; ++fn)
          acc[fm][fn] = __builtin_amdgcn_mfma_f32_16x16x32_bf16(a[fm], bb[fn], acc[fm][fn], 0, 0, 0);
    }
  }
  bf16_t* qb = qfT2 + (size_t)b * HW_ * CQ;
  bf16_t* kb = kfT2 + (size_t)b * HW_ * CQ;
  bf16_t* Vb = Vp2 + (size_t)b * CIN * HW_;
#pragma unroll
  for (int fm = 0; fm < 4; ++fm) {
#pragma unroll
    for (int j = 0; j < 4; ++j) {
      int m = m0 + wm * 64 + fm * 16 + g * 4 + j;
      float bias = (m < 64) ? bq[m] : (m < 128) ? bk[m - 64] : bv[m - 128];
#pragma unroll
      for (int fn = 0; fn < 4; ++fn) {
        int n = n0 + wn * 64 + fn * 16 + cc;   // permuted-pixel index p'
        float val = acc[fm][fn][j] + bias;
        if (m < 64)       qb[(size_t)n * CQ + m] = (bf16_t)val;        // qfT2[p'][m]
        else if (m < 128) kb[(size_t)n * CQ + (m - 64)] = (bf16_t)val; // kfT2[p'][m-64]
        else              Vb[(size_t)(m - 128) * HW_ + n] = (bf16_t)val;
      }
    }
  }
}

// ---------------- energy + softmax(v) -> Pt[b][w][k][v][h] ----------------
// Q rows j = w0*64 + rr (contiguous 128); K rows j = rr*64 + ky (stride-64).
// LDS contents identical to v10 -> fragment/softmax/P-write code unchanged.
__global__ __launch_bounds__(256) void k_energy(const bf16_t* __restrict__ qfT2,
                                                const bf16_t* __restrict__ kfT2,
                                                bf16_t* __restrict__ Pt, int zbase) {
  __shared__ bf16_t Qs[8192];       // 16KB
  __shared__ bf16_t Ks[2][4096];    // 2x8KB
  const int lin = blockIdx.x + blockIdx.y * 32 + blockIdx.z * 512;
  const int total = 512 * gridDim.z, chunk = total >> 3;
  const int orig = (lin & 7) * chunk + (lin >> 3);  // bijective
  const int bx = orig & 31, by = (orig >> 5) & 15, bz = orig >> 9;
  const int b = zbase + bz;
  const int w0 = bx * 2, ky0 = by * 4;
  const char* qb = (const char*)(qfT2 + (size_t)b * HW_ * CQ);
  const char* kb = (const char*)(kfT2 + (size_t)b * HW_ * CQ);
  bf16_t* Ptb = Pt + (size_t)bz * 16777216;
  const int tid = threadIdx.x, wv_ = tid >> 6, lane = tid & 63;
  const int g = lane >> 4, cc = lane & 15;

  // stage Q: rows w0*64 .. w0*64+127 (contiguous)
#pragma unroll
  for (int i = 0; i < 4; ++i) {
    int ch = wv_ * 4 + i;
    int rr = ch * 8 + (lane >> 3);
    int sl = (lane & 7) ^ (rr & 7);
    gload16(qb + (size_t)(w0 * 64 + rr) * 128 + sl * 16, (char*)Qs + ch * 1024);
  }
  // stage K(ky0): rows rr*64 + ky0 (stride-64)
  const char* kSb[2];
#pragma unroll
  for (int i = 0; i < 2; ++i) {
    int ch = wv_ * 2 + i;
    int rr = ch * 8 + (lane >> 3);
    int sl = (lane & 7) ^ (rr & 7);
    kSb[i] = kb + (size_t)rr * 8192 + ky0 * 128 + sl * 16;
    gload16(kSb[i], (char*)Ks[0] + ch * 1024);
  }
  asm volatile("s_waitcnt vmcnt(0)" ::: "memory");
  __builtin_amdgcn_s_barrier();

  bf16x8 qf[2][2];
#pragma unroll
  for (int fm = 0; fm < 2; ++fm)
#pragma unroll
    for (int k2 = 0; k2 < 2; ++k2)
      qf[fm][k2] = *(const bf16x8*)((char*)Qs + (wv_ * 32 + fm * 16 + cc) * 128 +
                                    (((k2 * 4 + g) ^ (cc & 7)) * 16));

  const int w = w0 + (wv_ >> 1);
  for (int kq = 0; kq < 4; ++kq) {
    const int cur = kq & 1;
    if (kq < 3) {
      const int nxt = cur ^ 1;
#pragma unroll
      for (int i = 0; i < 2; ++i) {
        int ch = wv_ * 2 + i;
        gload16(kSb[i] + (kq + 1) * 128, (char*)Ks[nxt] + ch * 1024);
      }
      asm volatile("s_waitcnt vmcnt(2)" ::: "memory");
    } else {
      asm volatile("s_waitcnt vmcnt(0)" ::: "memory");
    }
    __builtin_amdgcn_s_barrier();

    f32x4 acc[2][4]{};
#pragma unroll
    for (int k2 = 0; k2 < 2; ++k2) {
      bf16x8 kf[4];
#pragma unroll
      for (int f = 0; f < 4; ++f)
        kf[f] = *(const bf16x8*)((char*)Ks[cur] + (f * 16 + cc) * 128 + (((k2 * 4 + g) ^ (cc & 7)) * 16));
#pragma unroll
      for (int fm = 0; fm < 2; ++fm)
#pragma unroll
        for (int fn = 0; fn < 4; ++fn)
          acc[fm][fn] = __builtin_amdgcn_mfma_f32_16x16x32_bf16(qf[fm][k2], kf[fn], acc[fm][fn], 0, 0, 0);
    }
#pragma unroll
    for (int fm = 0; fm < 2; ++fm) {
      float e[4][4], invj[4];
#pragma unroll
      for (int j = 0; j < 4; ++j) {
        float mx = fmaxf(fmaxf(acc[fm][0][j], acc[fm][1][j]), fmaxf(acc[fm][2][j], acc[fm][3][j]));
#pragma unroll
        for (int d = 1; d < 16; d <<= 1) mx = fmaxf(mx, __shfl_xor(mx, d, 64));
        float s = 0.f;
#pragma unroll
        for (int fn = 0; fn < 4; ++fn) { e[fn][j] = __expf(acc[fm][fn][j] - mx); s += e[fn][j]; }
#pragma unroll
        for (int d = 1; d < 16; d <<= 1) s += __shfl_xor(s, d, 64);
        invj[j] = __builtin_amdgcn_rcpf(s);
      }
      int h0 = (wv_ & 1) * 32 + fm * 16 + g * 4;
#pragma unroll
      for (int fn = 0; fn < 4; ++fn) {
        int v = fn * 16 + cc;
        bf16x4 pk = { (bf16_t)(e[fn][0] * invj[0]), (bf16_t)(e[fn][1] * invj[1]),
                      (bf16_t)(e[fn][2] * invj[2]), (bf16_t)(e[fn][3] * invj[3]) };
        *(bf16x4*)&Ptb[(((size_t)w * 64 + (ky0 + kq)) * 64 + v) * 64 + h0] = pk;
      }
    }
    asm volatile("s_waitcnt lgkmcnt(0)" ::: "memory");
    __builtin_amdgcn_s_barrier();
  }
}

// ---------------- out GEMM v11 + epilogue (unchanged) ----------------
#define KSTEP_S(s, cur, nxt) do {                                                            \
    _Pragma("unroll")                                                                        \
    for (int r = 0; r < 4; ++r)                                                              \
      gload16(aSb[r] + (size_t)((s) + 1) * 128, Ls + (nxt) * 49152 + (r * 8 + wv_) * 1024);  \
    _Pragma("unroll")                                                                        \
    for (int r = 0; r < 2; ++r)                                                              \
      gload16(bSb[r] + (size_t)((s) + 1) * 8192,                                             \
              Ls + (nxt) * 49152 + 32768 + (r * 8 + wv_) * 1024);                            \
    asm volatile("s_waitcnt vmcnt(6)" ::: "memory");                                         \
    __builtin_amdgcn_s_barrier();                                                            \
    COMPUTE(cur);                                                                            \
  } while (0)

#define COMPUTE(cur) do {                                                                    \
    const char* base_ = Ls + (cur) * 49152;                                                  \
    _Pragma("unroll")                                                                        \
    for (int k2 = 0; k2 < 2; ++k2) {                                                         \
      bf16x8 a[4], bb[4];                                                                    \
      _Pragma("unroll")                                                                      \
      for (int fm = 0; fm < 4; ++fm) a[fm] = *(const bf16x8*)(base_ + aoff[k2][fm]);         \
      _Pragma("unroll")                                                                      \
      for (int fn = 0; fn < 4; ++fn) bb[fn] = *(const bf16x8*)(base_ + boff[k2][fn]);        \
      _Pragma("unroll")                                                                      \
      for (int fm = 0; fm < 4; ++fm)                                                         \
        _Pragma("unroll")                                                                    \
        for (int fn = 0; fn < 4; ++fn)                                                       \
          acc[fm][fn] = __builtin_amdgcn_mfma_f32_16x16x32_bf16(a[fm], bb[fn], acc[fm][fn], 0, 0, 0); \
    }                                                                                        \
  } while (0)

__global__ __launch_bounds__(512) void k_out(const bf16_t* __restrict__ Vp2,
                                             const bf16_t* __restrict__ Pt,
                                             const float* __restrict__ x,
                                             const float* __restrict__ gamma,
                                             float* __restrict__ outp, int zbase) {
  __shared__ char Ls[147456];  // 3 x 48KB
  const int lin = blockIdx.x + (blockIdx.y << 1) + (blockIdx.z << 6);
  const int nwg8 = (gridDim.z == 4) ? 32 : 8;
  const int rsw = (lin & 7) * nwg8 + (lin >> 3);
  const int c0 = (rsw & 1) * 256;
  const int w0 = ((rsw >> 1) & 31) * 2;
  const int bz = (gridDim.z == 4) ? (rsw >> 6) : 0;
  const int b = zbase + bz;
  const char* Vb = (const char*)(Vp2 + (size_t)b * CIN * HW_);
  const char* Pb = (const char*)(Pt + (size_t)bz * 16777216);
  const int tid = threadIdx.x, wv_ = tid >> 6, lane = tid & 63;
  const int wm = wv_ >> 1, wn = wv_ & 1;
  const int g = lane >> 4, cc = lane & 15;

  const char* aSb[4]; const char* bSb[2];
#pragma unroll
  for (int r = 0; r < 4; ++r) {
    int L = (r * 8 + wv_) * 64 + lane;
    int arow = L >> 3, asl = (L & 7) ^ (arow & 7);
    aSb[r] = Vb + (size_t)(c0 + arow) * 8192 + asl * 16;
  }
#pragma unroll
  for (int r = 0; r < 2; ++r) {
    int L = (r * 8 + wv_) * 64 + lane;
    int ws = L >> 9, e = L & 511, v = e >> 3, bsl = (e & 7) ^ (v & 7);
    bSb[r] = Pb + (size_t)(w0 + ws) * 524288 + v * 128 + bsl * 16;
  }
  int aoff[2][4], boff[2][4];
#pragma unroll
  for (int k2 = 0; k2 < 2; ++k2) {
#pragma unroll
    for (int fm = 0; fm < 4; ++fm)
      aoff[k2][fm] = (wm * 64 + fm * 16 + cc) * 128 + (((k2 * 4 + g) ^ (cc & 7)) * 16);
#pragma unroll
    for (int fn = 0; fn < 4; ++fn)
      boff[k2][fn] = 32768 + wn * 8192 + (fn * 16 + cc) * 128 + (((k2 * 4 + g) ^ (cc & 7)) * 16);
  }

  f32x4 acc[4][4]{};
#pragma unroll
  for (int r = 0; r < 4; ++r) gload16(aSb[r], Ls + (r * 8 + wv_) * 1024);
#pragma unroll
  for (int r = 0; r < 2; ++r) gload16(bSb[r], Ls + 32768 + (r * 8 + wv_) * 1024);

  int s = 0;
#pragma unroll 1
  for (int t = 0; t < 21; ++t) {
    KSTEP_S(s, 0, 1);
    KSTEP_S(s + 1, 1, 2);
    KSTEP_S(s + 2, 2, 0);
    s += 3;
  }
  asm volatile("s_waitcnt vmcnt(0)" ::: "memory");
  __builtin_amdgcn_s_barrier();
  COMPUTE(0);

  const float gmm = gamma[0];
  const float* xb = x + (size_t)b * CIN * HW_;
  float* ob = outp + (size_t)b * CIN * HW_;
  const int w = w0 + wn;
#pragma unroll
  for (int fm = 0; fm < 4; ++fm) {
#pragma unroll
    for (int jj = 0; jj < 4; ++jj) {
      int c = c0 + wm * 64 + fm * 16 + g * 4 + jj;
#pragma unroll
      for (int fn = 0; fn < 4; ++fn) {
        int n = w * 64 + fn * 16 + cc;
        size_t idx = (size_t)c * HW_ + n;
        ob[idx] = gmm * acc[fm][fn][jj] + xb[idx];
      }
    }
  }
}

extern "C" void kernel_launch(void* const* d_in, const int* in_sizes, int n_in,
                              void* d_out, int out_size, void* d_ws, size_t ws_size,
                              hipStream_t stream) {
  const float* x  = (const float*)d_in[0];
  const float* wq = (const float*)d_in[1];
  const float* bq = (const float*)d_in[2];
  const float* wk = (const float*)d_in[3];
  const float* bk = (const float*)d_in[4];
  const float* wv = (const float*)d_in[5];
  const float* bv = (const float*)d_in[6];
  const float* gamma = (const float*)d_in[7];
  float* outp = (float*)d_out;
  char* ws = (char*)d_ws;
  size_t off = 0;
  bf16_t* xT   = (bf16_t*)(ws + off); off += (size_t)4 * HW_ * CIN * 2;   // 16 MB
  bf16_t* Wcat = (bf16_t*)(ws + off); off += (size_t)640 * CIN * 2;       // 640 KB
  bf16_t* qfT2 = (bf16_t*)(ws + off); off += (size_t)4 * HW_ * CQ * 2;    // 2 MB
  bf16_t* kfT2 = (bf16_t*)(ws + off); off += (size_t)4 * HW_ * CQ * 2;    // 2 MB
  bf16_t* Vp2  = (bf16_t*)(ws + off); off += (size_t)4 * CIN * HW_ * 2;   // 16 MB
  bf16_t* Pt   = (bf16_t*)(ws + off);
  const size_t pbytes = (size_t)HW_ * HW_ * 2;                            // 32 MB / batch
  const bool full = (ws_size >= off + 4 * pbytes);

  k_wcat<<<dim3(320), dim3(256), 0, stream>>>(wq, wk, wv, Wcat);
  k_prep<<<dim3(64, 8, 4), dim3(256), 0, stream>>>(x, xT);
  k_proj<<<dim3(32, 5, 4), dim3(256), 0, stream>>>(Wcat, xT, bq, bk, bv, qfT2, kfT2, Vp2);
  if (full) {
    k_energy<<<dim3(32, 16, 4), dim3(256), 0, stream>>>(qfT2, kfT2, Pt, 0);
    k_out<<<dim3(2, 32, 4), dim3(512), 0, stream>>>(Vp2, Pt, x, gamma, outp, 0);
  } else {
    for (int b = 0; b < 4; ++b) {
      k_energy<<<dim3(32, 16, 1), dim3(256), 0, stream>>>(qfT2, kfT2, Pt, b);
      k_out<<<dim3(2, 32, 1), dim3(512), 0, stream>>>(Vp2, Pt, x, gamma, outp, b);
    }
  }
}